// Round 3
// baseline (1862.917 us; speedup 1.0000x reference)
//
#include <hip/hip_runtime.h>
#include <cstdint>
#include <cstddef>

// nODE: 50 Euler steps of  x <- x*(1+dt*gamma) + dt*tanh(x @ W^T + b)
// Round 8: 32x32x16 MFMA + 4-deep B ring prefetch.
//  - Cycle model (post R7): wall/step/CU ~36.9k cyc; matrix 9.9k, LDS 10.2k,
//    VALU 8k -- three parallel pipes at ~25% each, ~55% correlated stalls
//    (B-load latency through a 1-slice window + barrier/Euler matrix idle).
//  - mfma_f32_32x32x16_bf16: 15% faster pipe rate (m119), half the MFMA
//    instructions (128/wave/step), same LDS read bytes. C-layout: col=lane&31,
//    row=(reg&3)+8*(reg>>2)+4*(lane>>5) (m74-verified). State-hi writes become
//    64x ds_write_b16 (1 col/lane) -- acceptable DS cost.
//  - B ring bfr[4][2]: prefetch k-slice ks+3 while computing ks (~780
//    wave-visible cyc cover -> L3 latency hidden). Ring wraps across steps
//    (W is step-invariant): next step's first slices are in flight DURING
//    Euler + barrier.
//  - Register persistence of B dropped (R7: zero FETCH effect, -6% perf).
//  - Single barrier/step via ldsA double-buffer; setprio(1) around MFMA.

#define D_DIM 512
#define NSTEPS 50
#define A_STRIDE 520   // elems; row = 1040 B (16B-aligned)

typedef __bf16 bf16x8 __attribute__((ext_vector_type(8)));
typedef float f32x16 __attribute__((ext_vector_type(16)));
typedef unsigned short ushort8_t __attribute__((ext_vector_type(8)));

__device__ __forceinline__ unsigned short f_to_bf16_bits(float f) {
    union { float f; unsigned int i; } c;
    c.f = f;
    unsigned int u = c.i;
    unsigned int r = (u + 0x7fffu + ((u >> 16) & 1u)) >> 16;  // RNE
    return (unsigned short)r;
}

// Wl frag layout for 32x32x16 B-frags:
//   f = ((w*32 + ks)*2 + cg)*64 + lane, elems [f*8+j] =
//   bf16( W[w*64 + cg*32 + (lane&31)][ks*16 + (lane>>5)*8 + j] )
// (B-frag: col = lane&31, k = (lane>>5)*8 + j; W[col][k] is the B operand for
//  y = x @ W^T.)
__global__ __launch_bounds__(256) void build_wl2(
    const float* __restrict__ W, unsigned short* __restrict__ Wl) {
    int f = blockIdx.x * 256 + threadIdx.x;    // 0..32767
    int lane = f & 63;
    int cg   = (f >> 6) & 1;
    int ks   = (f >> 7) & 31;
    int w    = f >> 12;
    int col  = w * 64 + cg * 32 + (lane & 31);
    int k0   = ks * 16 + (lane >> 5) * 8;
    float4 a = *(const float4*)&W[(size_t)col * D_DIM + k0];
    float4 b = *(const float4*)&W[(size_t)col * D_DIM + k0 + 4];
    ushort8_t o;
    o[0] = f_to_bf16_bits(a.x); o[1] = f_to_bf16_bits(a.y);
    o[2] = f_to_bf16_bits(a.z); o[3] = f_to_bf16_bits(a.w);
    o[4] = f_to_bf16_bits(b.x); o[5] = f_to_bf16_bits(b.y);
    o[6] = f_to_bf16_bits(b.z); o[7] = f_to_bf16_bits(b.w);
    *(ushort8_t*)&Wl[(size_t)f * 8] = o;
}

__global__ __launch_bounds__(512, 2) void node_persist(
    const float* __restrict__ X,              // fp32 [32768][512]
    const unsigned short* __restrict__ Wl,    // bf16 frag-sequential W
    const float* __restrict__ bias,           // [512]
    const float* __restrict__ gamma,          // [512]
    float* __restrict__ Fout)                 // fp32 [32768][512]
{
    __shared__ unsigned short ldsA[2][64 * A_STRIDE];   // 2 x 66,560 B

    const int tid  = threadIdx.x;
    const int lane = tid & 63;
    const int w    = tid >> 6;        // wave 0..7 -> col strip [w*64, w*64+64)
    const int l32  = lane & 31;
    const int kh   = lane >> 5;       // k-half (0/1)
    const int bm   = blockIdx.x;      // 0..511, rows [bm*64, bm*64+64)
    const float dt = 1.0f / 50.0f;

    // Per-lane column constants: col(cg) = w*64 + cg*32 + l32 (one col/lane!)
    float bc_[2], g1_[2];
#pragma unroll
    for (int cg = 0; cg < 2; ++cg) {
        int c = w * 64 + cg * 32 + l32;
        bc_[cg] = bias[c];
        g1_[cg] = 1.0f + dt * gamma[c];
    }

    // B base pointer; frag (ks,cg) at + ks*1024 + cg*512 elems.
    const unsigned short* bpw = Wl + (size_t)w * 32768 + (size_t)lane * 8;

    // State in C-layout: s[rg][cg][reg] = state of
    //   row = bm*64 + rg*32 + (reg&3) + 8*(reg>>2) + 4*kh, col = w*64+cg*32+l32
    float s[2][2][16];
#pragma unroll
    for (int rg = 0; rg < 2; ++rg)
#pragma unroll
        for (int cg = 0; cg < 2; ++cg)
#pragma unroll
            for (int reg = 0; reg < 16; ++reg) {
                int row = bm * 64 + rg * 32 + (reg & 3) + 8 * (reg >> 2) + 4 * kh;
                int col = w * 64 + cg * 32 + l32;
                s[rg][cg][reg] = X[(size_t)row * D_DIM + col];
            }

    // Initial state-hi into ldsA[0] (b16 writes; lanes span 32 consecutive
    // cols -> 2-way bank aliasing = free).
#pragma unroll
    for (int rg = 0; rg < 2; ++rg) {
        unsigned short* wb =
            &ldsA[0][(rg * 32 + 4 * kh) * A_STRIDE + w * 64 + l32];
#pragma unroll
        for (int cg = 0; cg < 2; ++cg)
#pragma unroll
            for (int reg = 0; reg < 16; ++reg)
                wb[((reg & 3) + 8 * (reg >> 2)) * A_STRIDE + cg * 32] =
                    f_to_bf16_bits(s[rg][cg][reg]);
    }

    // Prime B ring with k-slices 0..2 (distance-3 prefetch).
    bf16x8 bfr[4][2];
#pragma unroll
    for (int i = 0; i < 3; ++i)
#pragma unroll
        for (int cg = 0; cg < 2; ++cg)
            bfr[i][cg] = *reinterpret_cast<const bf16x8*>(
                bpw + i * 1024 + cg * 512);

    __syncthreads();   // ldsA[0] fully written

    int p = 0;
    for (int step = 0; step < NSTEPS; ++step) {
        f32x16 acc[2][2];
#pragma unroll
        for (int rg = 0; rg < 2; ++rg)
#pragma unroll
            for (int cg = 0; cg < 2; ++cg) {
                f32x16 t;
#pragma unroll
                for (int j = 0; j < 16; ++j) t[j] = bc_[cg];
                acc[rg][cg] = t;   // bias folded into acc init
            }

        // A-frag double-buffer: prime slice 0 from current LDS buffer.
        bf16x8 afr[2][2];
#pragma unroll
        for (int rg = 0; rg < 2; ++rg)
            afr[0][rg] = *reinterpret_cast<const bf16x8*>(
                &ldsA[p][(rg * 32 + l32) * A_STRIDE + kh * 8]);

#pragma unroll
        for (int ks = 0; ks < 32; ++ks) {
            // Prefetch B slice ks+3 (wraps across steps: W is step-invariant,
            // so these loads stay in flight through Euler + barrier).
            {
                const unsigned short* bk = bpw + ((ks + 3) & 31) * 1024;
#pragma unroll
                for (int cg = 0; cg < 2; ++cg)
                    bfr[(ks + 3) & 3][cg] =
                        *reinterpret_cast<const bf16x8*>(bk + cg * 512);
            }
            // Prefetch A-frags for slice ks+1.
            if (ks < 31) {
#pragma unroll
                for (int rg = 0; rg < 2; ++rg)
                    afr[(ks + 1) & 1][rg] = *reinterpret_cast<const bf16x8*>(
                        &ldsA[p][(rg * 32 + l32) * A_STRIDE
                                 + (ks + 1) * 16 + kh * 8]);
            }
            __builtin_amdgcn_s_setprio(1);
#pragma unroll
            for (int rg = 0; rg < 2; ++rg)
#pragma unroll
                for (int cg = 0; cg < 2; ++cg)
                    acc[rg][cg] = __builtin_amdgcn_mfma_f32_32x32x16_bf16(
                        afr[ks & 1][rg], bfr[ks & 3][cg], acc[rg][cg], 0, 0, 0);
            __builtin_amdgcn_s_setprio(0);
        }

        // Euler update in registers (same formulation -> same numerics).
#pragma unroll
        for (int rg = 0; rg < 2; ++rg)
#pragma unroll
            for (int cg = 0; cg < 2; ++cg)
#pragma unroll
                for (int reg = 0; reg < 16; ++reg) {
                    float y = acc[rg][cg][reg];           // includes bias
                    float e = __expf(2.0f * y);
                    float th = 1.0f - 2.0f * __builtin_amdgcn_rcpf(e + 1.0f);
                    s[rg][cg][reg] = s[rg][cg][reg] * g1_[cg] + dt * th;
                }

        if (step == NSTEPS - 1) break;

        // Write next state-hi to the OTHER buffer; one barrier per step.
#pragma unroll
        for (int rg = 0; rg < 2; ++rg) {
            unsigned short* wb =
                &ldsA[p ^ 1][(rg * 32 + 4 * kh) * A_STRIDE + w * 64 + l32];
#pragma unroll
            for (int cg = 0; cg < 2; ++cg)
#pragma unroll
                for (int reg = 0; reg < 16; ++reg)
                    wb[((reg & 3) + 8 * (reg >> 2)) * A_STRIDE + cg * 32] =
                        f_to_bf16_bits(s[rg][cg][reg]);
        }
        __syncthreads();   // new buffer fully written
        p ^= 1;
    }

    // Final fp32 store (lanes cover 32 consecutive cols -> 128B segments).
#pragma unroll
    for (int rg = 0; rg < 2; ++rg)
#pragma unroll
        for (int cg = 0; cg < 2; ++cg)
#pragma unroll
            for (int reg = 0; reg < 16; ++reg) {
                int row = bm * 64 + rg * 32 + (reg & 3) + 8 * (reg >> 2) + 4 * kh;
                int col = w * 64 + cg * 32 + l32;
                Fout[(size_t)row * D_DIM + col] = s[rg][cg][reg];
            }
}

extern "C" void kernel_launch(void* const* d_in, const int* in_sizes, int n_in,
                              void* d_out, int out_size, void* d_ws, size_t ws_size,
                              hipStream_t stream) {
    const float* x  = (const float*)d_in[0];   // [32768][512]
    const float* W  = (const float*)d_in[1];   // [512][512]
    const float* bi = (const float*)d_in[2];   // [512]
    const float* ga = (const float*)d_in[3];   // [512]

    unsigned short* Wl = (unsigned short*)d_ws;   // 512 KB frag-sequential bf16 W

    build_wl2<<<128, 256, 0, stream>>>(W, Wl);
    node_persist<<<dim3(512), dim3(512), 0, stream>>>(
        x, Wl, bi, ga, (float*)d_out);
}

// Round 4
// 1605.373 us; speedup vs baseline: 1.1604x; 1.1604x over previous
//
#include <hip/hip_runtime.h>
#include <hip/hip_bf16.h>
#include <cstdint>
#include <cstddef>

// nODE: 50 Euler steps of  x <- x*(1+dt*gamma) + dt*tanh(x @ W^T + b)
// Round 9 = R5 (best known, 1537us) + ONE change: B prefetch ring deepened
// from 2 to 4 slices (distance-3 ~= 930 SIMD-cyc > L2-miss latency).
// Rationale: wall ~= FETCH/3.3TB/s across R5-R8; all four had prefetch
// distance 250-400cyc < miss latency (~600-900cyc). This round distinguishes
// latency-drain (expect ~1050-1250us, FETCH flat) from a hard L2-miss
// bandwidth ceiling (expect no change -> next round cuts fetch volume).
// Everything else bit-identical to R5: Wb layout, bp addressing, LDS single
// buffer + 2 barriers, slice order 0..15, Euler formulation.

#define D_DIM 512
#define BATCH_N 32768
#define NSTEPS 50
#define A_STRIDE 520   // elems; row = 1040 B (16B-aligned, bank-uniform reads)

typedef __bf16 bf16x8 __attribute__((ext_vector_type(8)));
typedef float f32x4 __attribute__((ext_vector_type(4)));

__device__ __forceinline__ float bf16_bits_to_f(unsigned short u) {
    union { unsigned int i; float f; } c;
    c.i = ((unsigned int)u) << 16;
    return c.f;
}
__device__ __forceinline__ unsigned short f_to_bf16_bits(float f) {
    union { float f; unsigned int i; } c;
    c.f = f;
    unsigned int u = c.i;
    unsigned int r = (u + 0x7fffu + ((u >> 16) & 1u)) >> 16;  // RNE
    return (unsigned short)r;
}

// Build row-permuted bf16 W: Wb[w*64+i][k] = W[w*64 + sigma(i)][k],
// sigma(i) = 4*(i&15) + (i>>4).
__global__ __launch_bounds__(256) void build_wperm(
    const float* __restrict__ W, unsigned short* __restrict__ Wb) {
    int e4 = blockIdx.x * 256 + threadIdx.x;   // 0..65535 (512*128 float4)
    int k4   = e4 & 127;
    int orow = e4 >> 7;
    int i    = orow & 63;
    int srow = (orow & ~63) | (4 * (i & 15) + (i >> 4));
    float4 v = ((const float4*)W)[srow * 128 + k4];
    ushort4 o;
    o.x = f_to_bf16_bits(v.x);
    o.y = f_to_bf16_bits(v.y);
    o.z = f_to_bf16_bits(v.z);
    o.w = f_to_bf16_bits(v.w);
    ((ushort4*)Wb)[orow * 128 + k4] = o;
}

__global__ __launch_bounds__(512, 2) void node_persist(
    const float* __restrict__ X,              // fp32 [32768][512]
    const unsigned short* __restrict__ Wb,    // bf16 row-permuted [512][512]
    const float* __restrict__ bias,           // [512]
    const float* __restrict__ gamma,          // [512]
    float* __restrict__ Fout)                 // fp32 [32768][512]
{
    __shared__ unsigned short ldsA[64 * A_STRIDE];   // 66,560 B state-hi

    const int tid  = threadIdx.x;
    const int lane = tid & 63;
    const int w    = tid >> 6;        // wave 0..7 -> col strip [w*64, w*64+64)
    const int l16  = lane & 15;
    const int quad = lane >> 4;
    const int bm   = blockIdx.x;      // 0..511, rows [bm*64, bm*64+64)
    const float dt = 1.0f / 50.0f;

    // Lane's 4 TRUE output cols: ctrue0..ctrue0+3 (thanks to W row-perm).
    const int ctrue0 = w * 64 + 4 * l16;

    // B-fragment global base pointers (per row-tile t). k offset = slice*32.
    const unsigned short* bp[4];
#pragma unroll
    for (int t = 0; t < 4; ++t)
        bp[t] = Wb + (size_t)(w * 64 + t * 16 + l16) * D_DIM + quad * 8;

    // Column constants (float4).
    float bc_[4], g1_[4];
    {
        float4 b4 = *(const float4*)&bias[ctrue0];
        float4 g4 = *(const float4*)&gamma[ctrue0];
        bc_[0] = b4.x; bc_[1] = b4.y; bc_[2] = b4.z; bc_[3] = b4.w;
        g1_[0] = 1.0f + dt * g4.x; g1_[1] = 1.0f + dt * g4.y;
        g1_[2] = 1.0f + dt * g4.z; g1_[3] = 1.0f + dt * g4.w;
    }

    // Initial state: float4 loads; s[tm][tn][r] = state of (row, ctrue0+tn).
    const int r0 = quad * 4;
    float s[4][4][4];
#pragma unroll
    for (int tm = 0; tm < 4; ++tm)
#pragma unroll
        for (int r = 0; r < 4; ++r) {
            float4 v = *(const float4*)
                &X[(size_t)(bm * 64 + r0 + tm * 16 + r) * D_DIM + ctrue0];
            s[tm][0][r] = v.x; s[tm][1][r] = v.y;
            s[tm][2][r] = v.z; s[tm][3][r] = v.w;
        }

    // Initial state-hi into ldsA (b64 writes, bank-uniform).
#pragma unroll
    for (int tm = 0; tm < 4; ++tm)
#pragma unroll
        for (int r = 0; r < 4; ++r) {
            ushort4 h;
            h.x = f_to_bf16_bits(s[tm][0][r]);
            h.y = f_to_bf16_bits(s[tm][1][r]);
            h.z = f_to_bf16_bits(s[tm][2][r]);
            h.w = f_to_bf16_bits(s[tm][3][r]);
            *(ushort4*)&ldsA[(r0 + tm * 16 + r) * A_STRIDE + ctrue0] = h;
        }

    // B ring: 4 slices deep (distance-3 prefetch). Prime slices 0..2.
    bf16x8 bfr[4][4];
#pragma unroll
    for (int i = 0; i < 3; ++i)
#pragma unroll
        for (int t = 0; t < 4; ++t)
            bfr[i][t] = *reinterpret_cast<const bf16x8*>(bp[t] + i * 32);

    __syncthreads();   // ldsA fully written

    for (int step = 0; step < NSTEPS; ++step) {
        f32x4 acc[4][4];
#pragma unroll
        for (int tm = 0; tm < 4; ++tm)
#pragma unroll
            for (int tn = 0; tn < 4; ++tn) {
                f32x4 b4 = {bc_[tn], bc_[tn], bc_[tn], bc_[tn]};
                acc[tm][tn] = b4;   // bias folded into acc init
            }

#pragma unroll
        for (int kb = 0; kb < 16; ++kb) {
            // Prefetch slice kb+3 (wraps to next step's slices 0..2 at the
            // tail; W is step-invariant so these stay in flight through
            // Euler + barriers).
#pragma unroll
            for (int t = 0; t < 4; ++t)
                bfr[(kb + 3) & 3][t] = *reinterpret_cast<const bf16x8*>(
                    bp[t] + ((kb + 3) & 15) * 32);
            // A fragments for slice kb from LDS.
            bf16x8 af[4];
#pragma unroll
            for (int tm = 0; tm < 4; ++tm)
                af[tm] = *reinterpret_cast<const bf16x8*>(
                    &ldsA[(tm * 16 + l16) * A_STRIDE + kb * 32 + quad * 8]);
            // 16 MFMAs for slice kb (ring slot kb&3 arrived 3 slices ago).
#pragma unroll
            for (int tm = 0; tm < 4; ++tm)
#pragma unroll
                for (int tn = 0; tn < 4; ++tn)
                    acc[tm][tn] = __builtin_amdgcn_mfma_f32_16x16x32_bf16(
                        af[tm], bfr[kb & 3][tn], acc[tm][tn], 0, 0, 0);
        }

        // Euler update in registers.
#pragma unroll
        for (int tm = 0; tm < 4; ++tm)
#pragma unroll
            for (int tn = 0; tn < 4; ++tn)
#pragma unroll
                for (int r = 0; r < 4; ++r) {
                    float y = acc[tm][tn][r];             // includes bias
                    float e = __expf(2.0f * y);
                    float th = 1.0f - 2.0f * __builtin_amdgcn_rcpf(e + 1.0f);
                    s[tm][tn][r] = s[tm][tn][r] * g1_[tn] + dt * th;
                }

        if (step == NSTEPS - 1) break;

        __syncthreads();   // all waves done reading ldsA
#pragma unroll
        for (int tm = 0; tm < 4; ++tm)
#pragma unroll
            for (int r = 0; r < 4; ++r) {
                ushort4 h;
                h.x = f_to_bf16_bits(s[tm][0][r]);
                h.y = f_to_bf16_bits(s[tm][1][r]);
                h.z = f_to_bf16_bits(s[tm][2][r]);
                h.w = f_to_bf16_bits(s[tm][3][r]);
                *(ushort4*)&ldsA[(r0 + tm * 16 + r) * A_STRIDE + ctrue0] = h;
            }
        __syncthreads();   // new state-hi visible
    }

    // Final fp32 store (float4, fully coalesced).
#pragma unroll
    for (int tm = 0; tm < 4; ++tm)
#pragma unroll
        for (int r = 0; r < 4; ++r) {
            float4 v;
            v.x = s[tm][0][r]; v.y = s[tm][1][r];
            v.z = s[tm][2][r]; v.w = s[tm][3][r];
            *(float4*)&Fout[(size_t)(bm * 64 + r0 + tm * 16 + r) * D_DIM + ctrue0] = v;
        }
}

extern "C" void kernel_launch(void* const* d_in, const int* in_sizes, int n_in,
                              void* d_out, int out_size, void* d_ws, size_t ws_size,
                              hipStream_t stream) {
    const float* x  = (const float*)d_in[0];   // [32768][512]
    const float* W  = (const float*)d_in[1];   // [512][512]
    const float* bi = (const float*)d_in[2];   // [512]
    const float* ga = (const float*)d_in[3];   // [512]

    unsigned short* Wb = (unsigned short*)d_ws;   // 512 KB row-permuted bf16 W

    build_wperm<<<256, 256, 0, stream>>>(W, Wb);
    node_persist<<<dim3(512), dim3(512), 0, stream>>>(
        x, Wb, bi, ga, (float*)d_out);
}

// Round 5
// 1543.195 us; speedup vs baseline: 1.2072x; 1.0403x over previous
//
#include <hip/hip_runtime.h>
#include <hip/hip_bf16.h>
#include <cstdint>
#include <cstddef>

// nODE: 50 Euler steps of  x <- x*(1+dt*gamma) + dt*tanh(x @ W^T + b)
// Round 10 = R5 (best known, 1537us) + ONE change: W replicated 8x in the
// workspace, each block reads the copy for its own XCD (s_getreg XCC_ID).
// Rationale: wall ~= FETCH/3.3TB/s invariant across R5-R9; ~35-47% of the
// 512KB W set reaches the fabric every step regardless of demand volume
// (R7) or prefetch depth (R9). A 512KB set cannot capacity-miss a 4MB L2
// -> requests are structurally forced to fabric and concentrate on the L3
// slices/channels backing ONE 512KB region shared by all 256 CUs.
// Replication spreads the physical target set 8x and privatizes each copy
// to 32 CUs. Everything else is bit-identical to R5.

#define D_DIM 512
#define BATCH_N 32768
#define NSTEPS 50
#define A_STRIDE 520   // elems; row = 1040 B (16B-aligned, bank-uniform reads)
#define WCOPY_ELEMS (D_DIM * D_DIM)   // 262144 ushort = 512 KB per copy

typedef __bf16 bf16x8 __attribute__((ext_vector_type(8)));
typedef float f32x4 __attribute__((ext_vector_type(4)));

__device__ __forceinline__ unsigned short f_to_bf16_bits(float f) {
    union { float f; unsigned int i; } c;
    c.f = f;
    unsigned int u = c.i;
    unsigned int r = (u + 0x7fffu + ((u >> 16) & 1u)) >> 16;  // RNE
    return (unsigned short)r;
}

// Build row-permuted bf16 W, replicated ncopies times:
//   Wb[c][w*64+i][k] = W[w*64 + sigma(i)][k], sigma(i) = 4*(i&15) + (i>>4).
__global__ __launch_bounds__(256) void build_wperm(
    const float* __restrict__ W, unsigned short* __restrict__ Wb) {
    int e4 = blockIdx.x * 256 + threadIdx.x;   // 0..65535 (512*128 float4)
    int copy = blockIdx.y;
    int k4   = e4 & 127;
    int orow = e4 >> 7;
    int i    = orow & 63;
    int srow = (orow & ~63) | (4 * (i & 15) + (i >> 4));
    float4 v = ((const float4*)W)[srow * 128 + k4];
    ushort4 o;
    o.x = f_to_bf16_bits(v.x);
    o.y = f_to_bf16_bits(v.y);
    o.z = f_to_bf16_bits(v.z);
    o.w = f_to_bf16_bits(v.w);
    ((ushort4*)Wb)[(size_t)copy * (WCOPY_ELEMS / 4) + orow * 128 + k4] = o;
}

__global__ __launch_bounds__(512, 2) void node_persist(
    const float* __restrict__ X,              // fp32 [32768][512]
    const unsigned short* __restrict__ Wb,    // bf16 row-permuted, replicated
    const float* __restrict__ bias,           // [512]
    const float* __restrict__ gamma,          // [512]
    float* __restrict__ Fout,                 // fp32 [32768][512]
    int copy_mask)                            // ncopies-1 (pow2-1)
{
    __shared__ unsigned short ldsA[64 * A_STRIDE];   // 66,560 B state-hi

    const int tid  = threadIdx.x;
    const int lane = tid & 63;
    const int w    = tid >> 6;        // wave 0..7 -> col strip [w*64, w*64+64)
    const int l16  = lane & 15;
    const int quad = lane >> 4;
    const int bm   = blockIdx.x;      // 0..511, rows [bm*64, bm*64+64)
    const float dt = 1.0f / 50.0f;

    // Select this XCD's private W copy.
    unsigned int xcc;
    asm volatile("s_getreg_b32 %0, hwreg(HW_REG_XCC_ID)" : "=s"(xcc));
    const unsigned short* wbase =
        Wb + (size_t)(xcc & (unsigned)copy_mask) * WCOPY_ELEMS;

    // Lane's 4 TRUE output cols: ctrue0..ctrue0+3 (thanks to W row-perm).
    const int ctrue0 = w * 64 + 4 * l16;

    // B-fragment global base pointers (per row-tile t). k offset = slice*32.
    const unsigned short* bp[4];
#pragma unroll
    for (int t = 0; t < 4; ++t)
        bp[t] = wbase + (size_t)(w * 64 + t * 16 + l16) * D_DIM + quad * 8;

    // Column constants (float4).
    float bc_[4], g1_[4];
    {
        float4 b4 = *(const float4*)&bias[ctrue0];
        float4 g4 = *(const float4*)&gamma[ctrue0];
        bc_[0] = b4.x; bc_[1] = b4.y; bc_[2] = b4.z; bc_[3] = b4.w;
        g1_[0] = 1.0f + dt * g4.x; g1_[1] = 1.0f + dt * g4.y;
        g1_[2] = 1.0f + dt * g4.z; g1_[3] = 1.0f + dt * g4.w;
    }

    // Initial state: float4 loads; s[tm][tn][r] = state of (row, ctrue0+tn).
    const int r0 = quad * 4;
    float s[4][4][4];
#pragma unroll
    for (int tm = 0; tm < 4; ++tm)
#pragma unroll
        for (int r = 0; r < 4; ++r) {
            float4 v = *(const float4*)
                &X[(size_t)(bm * 64 + r0 + tm * 16 + r) * D_DIM + ctrue0];
            s[tm][0][r] = v.x; s[tm][1][r] = v.y;
            s[tm][2][r] = v.z; s[tm][3][r] = v.w;
        }

    // Initial state-hi into ldsA (b64 writes, bank-uniform).
#pragma unroll
    for (int tm = 0; tm < 4; ++tm)
#pragma unroll
        for (int r = 0; r < 4; ++r) {
            ushort4 h;
            h.x = f_to_bf16_bits(s[tm][0][r]);
            h.y = f_to_bf16_bits(s[tm][1][r]);
            h.z = f_to_bf16_bits(s[tm][2][r]);
            h.w = f_to_bf16_bits(s[tm][3][r]);
            *(ushort4*)&ldsA[(r0 + tm * 16 + r) * A_STRIDE + ctrue0] = h;
        }

    // Prime B register double-buffer with slice 0.
    bf16x8 bf0[4], bf1[4];
#pragma unroll
    for (int t = 0; t < 4; ++t)
        bf0[t] = *reinterpret_cast<const bf16x8*>(bp[t]);

    __syncthreads();   // ldsA fully written

    for (int step = 0; step < NSTEPS; ++step) {
        f32x4 acc[4][4];
#pragma unroll
        for (int tm = 0; tm < 4; ++tm)
#pragma unroll
            for (int tn = 0; tn < 4; ++tn) {
                f32x4 b4 = {bc_[tn], bc_[tn], bc_[tn], bc_[tn]};
                acc[tm][tn] = b4;   // bias folded into acc init
            }

#pragma unroll
        for (int kb2 = 0; kb2 < 8; ++kb2) {
            const int kb = kb2 * 2;
            // Prefetch slice kb+1 into bf1 (direct global->VGPR).
#pragma unroll
            for (int t = 0; t < 4; ++t)
                bf1[t] = *reinterpret_cast<const bf16x8*>(
                    bp[t] + ((kb + 1) & 15) * 32);
            {
                bf16x8 af[4];
#pragma unroll
                for (int t = 0; t < 4; ++t)
                    af[t] = *reinterpret_cast<const bf16x8*>(
                        &ldsA[(t * 16 + l16) * A_STRIDE + kb * 32 + quad * 8]);
#pragma unroll
                for (int tm = 0; tm < 4; ++tm)
#pragma unroll
                    for (int tn = 0; tn < 4; ++tn)
                        acc[tm][tn] = __builtin_amdgcn_mfma_f32_16x16x32_bf16(
                            af[tm], bf0[tn], acc[tm][tn], 0, 0, 0);
            }
            // Prefetch slice kb+2 (wraps to 0 -> ready for next step) into bf0.
#pragma unroll
            for (int t = 0; t < 4; ++t)
                bf0[t] = *reinterpret_cast<const bf16x8*>(
                    bp[t] + ((kb + 2) & 15) * 32);
            {
                bf16x8 af[4];
#pragma unroll
                for (int t = 0; t < 4; ++t)
                    af[t] = *reinterpret_cast<const bf16x8*>(
                        &ldsA[(t * 16 + l16) * A_STRIDE + (kb + 1) * 32 + quad * 8]);
#pragma unroll
                for (int tm = 0; tm < 4; ++tm)
#pragma unroll
                    for (int tn = 0; tn < 4; ++tn)
                        acc[tm][tn] = __builtin_amdgcn_mfma_f32_16x16x32_bf16(
                            af[tm], bf1[tn], acc[tm][tn], 0, 0, 0);
            }
        }

        // Euler update in registers.
#pragma unroll
        for (int tm = 0; tm < 4; ++tm)
#pragma unroll
            for (int tn = 0; tn < 4; ++tn)
#pragma unroll
                for (int r = 0; r < 4; ++r) {
                    float y = acc[tm][tn][r];             // includes bias
                    float e = __expf(2.0f * y);
                    float th = 1.0f - 2.0f * __builtin_amdgcn_rcpf(e + 1.0f);
                    s[tm][tn][r] = s[tm][tn][r] * g1_[tn] + dt * th;
                }

        if (step == NSTEPS - 1) break;

        __syncthreads();   // all waves done reading ldsA
#pragma unroll
        for (int tm = 0; tm < 4; ++tm)
#pragma unroll
            for (int r = 0; r < 4; ++r) {
                ushort4 h;
                h.x = f_to_bf16_bits(s[tm][0][r]);
                h.y = f_to_bf16_bits(s[tm][1][r]);
                h.z = f_to_bf16_bits(s[tm][2][r]);
                h.w = f_to_bf16_bits(s[tm][3][r]);
                *(ushort4*)&ldsA[(r0 + tm * 16 + r) * A_STRIDE + ctrue0] = h;
            }
        __syncthreads();   // new state-hi visible
    }

    // Final fp32 store (float4, fully coalesced).
#pragma unroll
    for (int tm = 0; tm < 4; ++tm)
#pragma unroll
        for (int r = 0; r < 4; ++r) {
            float4 v;
            v.x = s[tm][0][r]; v.y = s[tm][1][r];
            v.z = s[tm][2][r]; v.w = s[tm][3][r];
            *(float4*)&Fout[(size_t)(bm * 64 + r0 + tm * 16 + r) * D_DIM + ctrue0] = v;
        }
}

extern "C" void kernel_launch(void* const* d_in, const int* in_sizes, int n_in,
                              void* d_out, int out_size, void* d_ws, size_t ws_size,
                              hipStream_t stream) {
    const float* x  = (const float*)d_in[0];   // [32768][512]
    const float* W  = (const float*)d_in[1];   // [512][512]
    const float* bi = (const float*)d_in[2];   // [512]
    const float* ga = (const float*)d_in[3];   // [512]

    unsigned short* Wb = (unsigned short*)d_ws;

    // 8 per-XCD copies if the workspace allows (4 MB); else single copy.
    int ncopies = (ws_size >= (size_t)8 * WCOPY_ELEMS * sizeof(unsigned short))
                      ? 8 : 1;

    build_wperm<<<dim3(256, ncopies), 256, 0, stream>>>(W, Wb);
    node_persist<<<dim3(512), dim3(512), 0, stream>>>(
        x, Wb, bi, ga, (float*)d_out, ncopies - 1);
}